// Round 10
// baseline (175.770 us; speedup 1.0000x reference)
//
#include <hip/hip_runtime.h>
#include <hip/hip_fp16.h>

// RoIAlignRotated on MI355X — R11.
// R10 post-mortem: banded sort key null (-0.7us, within noise). Diagnosis of
// WHY: transpose grid (4,4,400) dispatches x-fastest -> XCD = (bx+4by)%8,
// independent of y. Each XCD's L2 ends the transpose holding (x,c)-COLUMNS
// spanning all y — but main's bucket k wants a contiguous y-STRIPE. Producer/
// consumer placement mismatch: every first-touch gather misses to L3 no
// matter how ROIs are sorted.
// R11 ("featT stripe-residency" package):
// 1) transpose grid re-dimensioned to (400,4,4), blockIdx.x = row index;
//    idx%8 = iy%8 -> row y' = (iy%8)*50 + iy/8 puts rows [50k,50k+50) on
//    XCD k — matching main's bucket-k cy-stripe. First-pass gathers hit the
//    L2 that just wrote them.
// 2) nontemporal feat loads: the 82MB read-once stream stops evicting the
//    freshly written featT from the producing L2.
// Main kernel, sort key, ranking: byte-identical to R10.

#define B_ 2
#define C_ 256
#define H_ 200
#define W_ 200
#define OUTHW 7
#define GRID_S 14          // OUTHW * sampling_ratio(2)
#define NSAMP 196          // 14*14
#define ELEMS (C_ * OUTHW * OUTHW)  // 12544
#define FEATT_BYTES ((size_t)B_ * H_ * W_ * C_ * sizeof(__half))  // 40,960,000

typedef float f4v __attribute__((ext_vector_type(4)));

// ---------- NCHW f32 -> NHWC fp16, LDS-tiled, + distributed ROI ranking ----
// grid (400, 4, 4): blockIdx.x = row slot, .y = c-tile, .z = x-tile
__global__ __launch_bounds__(256) void transpose_h_kernel(
    const float* __restrict__ feat, __half* __restrict__ featT,
    const float* __restrict__ rois, int* __restrict__ perm, int N)
{
    __shared__ float tile[64][65];   // [c_local][x_local], stride 65
    const int iy   = blockIdx.x;             // 0..399, fastest-dispatched
    const int yb   = (iy & 7) * 50 + (iy >> 3);  // XCD (iy%8) owns rows [50k,50k+50)
    const int c0   = blockIdx.y * 64;
    const int x0   = blockIdx.z * 64;
    const int y    = yb % H_;
    const int b    = yb / H_;
    const int t    = threadIdx.x;
    const int nx   = min(64, W_ - x0);   // 64 or 8 (200 = 3*64 + 8): mult of 4

    // load: nontemporal float4 per lane along x -> 1KB per wave-instruction.
    const int xq  = (t & 15) * 4;    // 0,4,...,60
    const int cl0 = t >> 4;          // 0..15
    if (xq < nx) {
        #pragma unroll
        for (int i = 0; i < 4; ++i) {
            const int cl = cl0 + 16 * i;
            const f4v v = __builtin_nontemporal_load(
                reinterpret_cast<const f4v*>(
                    &feat[((size_t)(b * C_ + c0 + cl) * H_ + y) * W_ + x0 + xq]));
            // scalar LDS writes: 2 lanes/bank -> free
            tile[cl][xq + 0] = v[0];
            tile[cl][xq + 1] = v[1];
            tile[cl][xq + 2] = v[2];
            tile[cl][xq + 3] = v[3];
        }
    }
    __syncthreads();

    // write: each lane packs 8 contiguous channels of one pixel -> 16B store.
    // Wave covers 8 pixels x 64 channels: 8 x 128B full-cache-line segments.
    const int c = (t & 7) * 8;
    #pragma unroll
    for (int pass = 0; pass < 2; ++pass) {
        const int p = pass * 32 + (t >> 3);
        if (p < nx) {
            union { __half h[8]; uint4 u; } pk;
            #pragma unroll
            for (int k = 0; k < 8; ++k)
                pk.h[k] = __float2half(tile[c + k][p]);
            *reinterpret_cast<uint4*>(
                &featT[((size_t)(b * H_ + y) * W_ + x0 + p) * C_ + c0 + c]) = pk.u;
        }
    }

    // ---- distributed ROI ranking: the 16 FIRST-dispatched blocks
    // (iy<16, by==bz==0), 64 ROIs each, hidden under the other 6384 blocks.
    // key = (batch, cy-band of 32 scaled px, cx): slots disjoint, exact fp32.
    if (blockIdx.y == 0 && blockIdx.z == 0 && iy < 16) {
        float* s_key = &tile[0][0];      // 1024 floats available (16.6KB)
        const int id = iy;               // 0..15
        __syncthreads();                 // tile reads above are done
        if (N <= 1024) {
            for (int j = t; j < N; j += 256)
                s_key[j] = rois[j * 6 + 0] * 1.0e6f
                         + floorf(rois[j * 6 + 2] * (1.0f / 128.0f)) * 1.0e3f
                         + rois[j * 6 + 1];
            __syncthreads();
            const int i = id * 64 + t;   // t<64 active
            if (t < 64 && i < N) {
                const float ki = s_key[i];
                int r = 0;
                #pragma unroll 8
                for (int j = 0; j < N; ++j) {   // LDS broadcast, 8 in flight
                    const float kj = s_key[j];
                    r += (int)((kj < ki) | ((kj == ki) & (j < i)));
                }
                perm[r] = i;             // ranks distinct -> bijective
            }
        } else {
            for (int i = id * 64 + t; i < N; i += 1024)
                perm[i] = i;             // identity fallback
        }
    }
}

// ---------- per-roi sample table (channel-independent) ----------
__device__ __forceinline__ void build_table(
    const float* __restrict__ rois, int n, int t,
    float s_w[4][NSAMP], int s_idx[4][NSAMP], int pix_stride, int fold_batch,
    int* s_b)
{
    const float spatial_scale = 0.25f;
    if (t == 0 && s_b) *s_b = (int)rois[n * 6 + 0];
    if (t < NSAMP) {
        const int   b  = (int)rois[n * 6 + 0];
        const float cx = rois[n * 6 + 1] * spatial_scale;
        const float cy = rois[n * 6 + 2] * spatial_scale;
        const float rw = fmaxf(rois[n * 6 + 3] * spatial_scale, 1.0f);
        const float rh = fmaxf(rois[n * 6 + 4] * spatial_scale, 1.0f);
        const float th = rois[n * 6 + 5];
        const float cosv = cosf(th), sinv = sinf(th);

        const float bin_h = rh * (1.0f / OUTHW);
        const float bin_w = rw * (1.0f / OUTHW);
        const int row = t / GRID_S;
        const int col = t % GRID_S;

        const float yy = -rh * 0.5f + ((float)row + 0.5f) * 0.5f * bin_h;
        const float xx = -rw * 0.5f + ((float)col + 0.5f) * 0.5f * bin_w;

        const float y = yy * cosv - xx * sinv + cy;
        const float x = yy * sinv + xx * cosv + cx;

        const bool inside = (y >= -1.0f) && (y <= (float)H_) &&
                            (x >= -1.0f) && (x <= (float)W_);

        const float yc = fmaxf(y, 0.0f);
        const float xc = fmaxf(x, 0.0f);
        const float fy = floorf(yc);
        const float fx = floorf(xc);
        int yl = min((int)fy, H_ - 1);
        int xl = min((int)fx, W_ - 1);
        const int yh = min(yl + 1, H_ - 1);
        const int xh = min(xl + 1, W_ - 1);
        const float ly = (fy >= (float)(H_ - 1)) ? 0.0f : (yc - fy);
        const float lx = (fx >= (float)(W_ - 1)) ? 0.0f : (xc - fx);
        const float hy = 1.0f - ly;
        const float hx = 1.0f - lx;

        const float m = inside ? 0.25f : 0.0f;   // fold inside-mask + 2x2 mean
        s_w[0][t] = hy * hx * m;
        s_w[1][t] = hy * lx * m;
        s_w[2][t] = ly * hx * m;
        s_w[3][t] = ly * lx * m;
        const int bb = fold_batch ? b : 0;
        s_idx[0][t] = ((bb * H_ + yl) * W_ + xl) * pix_stride;
        s_idx[1][t] = ((bb * H_ + yl) * W_ + xh) * pix_stride;
        s_idx[2][t] = ((bb * H_ + yh) * W_ + xl) * pix_stride;
        s_idx[3][t] = ((bb * H_ + yh) * W_ + xh) * pix_stride;
    }
}

// ---------- main kernel: whole ROI per block, XCD-bucketed ROI order --------
__global__ __launch_bounds__(256) void roi_main_nhwc_h(
    const __half* __restrict__ featT,
    const float* __restrict__ rois,
    const int* __restrict__ perm, int N,
    float* __restrict__ out)
{
    __shared__ float  s_w[4][NSAMP];        // 3136 B
    __shared__ int    s_idx[4][NSAMP];      // 3136 B
    __shared__ __half s_out[49][258];       // 25284 B; total ~31.6 KB

    // bucket k (=XCD via native %8 round-robin) processes the k-th contiguous
    // chunk of the (batch,band,cx)-sorted ROI list; transpose placed that
    // stripe's rows on XCD k's L2.
    const int k = blockIdx.x & 7;
    const int j = blockIdx.x >> 3;
    const int q = N >> 3, rem = N & 7;
    const int sz = q + (k < rem ? 1 : 0);
    if (j >= sz) return;
    const int r = (k < rem ? k * (q + 1) : rem * (q + 1) + (k - rem) * q) + j;
    const int n = perm[r];

    const int t = threadIdx.x;
    build_table(rois, n, t, s_w, s_idx, C_, 1, nullptr);
    __syncthreads();

    const int lane  = t & 63;
    const int wave  = t >> 6;
    const int cbase = lane * 4;        // 4 channels per lane

    for (int bl = wave; bl < OUTHW * OUTHW; bl += 4) {
        const int oy = bl / OUTHW;
        const int ox = bl - oy * OUTHW;

        // ---- phase 1: read all 16 (weight, offset) pairs from LDS ----
        int   off[16];
        float w[16];
        #pragma unroll
        for (int jj = 0; jj < 2; ++jj) {
            #pragma unroll
            for (int i = 0; i < 2; ++i) {
                const int s = (oy * 2 + jj) * GRID_S + (ox * 2 + i);
                #pragma unroll
                for (int qq = 0; qq < 4; ++qq) {
                    const int kk = (jj * 2 + i) * 4 + qq;
                    w[kk]   = s_w[qq][s];
                    off[kk] = s_idx[qq][s] + cbase;
                }
            }
        }

        // ---- phase 2: issue the 16 x 8B gathers ----
        uint2 rv[16];
        #pragma unroll
        for (int kk = 0; kk < 16; ++kk)
            rv[kk] = *reinterpret_cast<const uint2*>(featT + off[kk]);

        __builtin_amdgcn_sched_barrier(0);

        // ---- phase 3: consume ----
        float a0 = 0.f, a1 = 0.f, a2 = 0.f, a3 = 0.f;
        #pragma unroll
        for (int kk = 0; kk < 16; ++kk) {
            const __half2* h2 = reinterpret_cast<const __half2*>(&rv[kk]);
            const float2 f0 = __half22float2(h2[0]);
            const float2 f1 = __half22float2(h2[1]);
            a0 += w[kk] * f0.x; a1 += w[kk] * f0.y;
            a2 += w[kk] * f1.x; a3 += w[kk] * f1.y;
        }

        s_out[bl][0 * 64 + lane] = __float2half(a0);
        s_out[bl][1 * 64 + lane] = __float2half(a1);
        s_out[bl][2 * 64 + lane] = __float2half(a2);
        s_out[bl][3 * 64 + lane] = __float2half(a3);
    }
    __syncthreads();

    // coalesced final stores: nontemporal stream
    float* __restrict__ ob = out + (size_t)n * ELEMS;
    for (int kk = 0; kk < 49; ++kk) {
        const int e   = t + kk * 256;
        const int c   = e / 49;
        const int bin = e - c * 49;
        __builtin_nontemporal_store(
            __half2float(s_out[bin][(c & 3) * 64 + (c >> 2)]), &ob[e]);
    }
}

// ---------- fallback (known-correct NCHW path, no workspace) ----------
__global__ __launch_bounds__(256) void roi_main_nchw(
    const float* __restrict__ feat,
    const float* __restrict__ rois,
    float* __restrict__ out)
{
    const int n = blockIdx.x;
    const int t = threadIdx.x;
    __shared__ float s_w[4][NSAMP];
    __shared__ int   s_idx[4][NSAMP];
    __shared__ int   s_b;

    build_table(rois, n, t, s_w, s_idx, 1, 0, &s_b);
    __syncthreads();

    const float* __restrict__ fb = feat + (size_t)s_b * (size_t)(C_ * H_ * W_);
    float* __restrict__ ob = out + (size_t)n * (size_t)ELEMS;

    for (int e = t; e < ELEMS; e += 256) {
        const int c   = e / 49;
        const int bin = e - c * 49;
        const int oy  = bin / 7;
        const int ox  = bin - oy * 7;
        const float* __restrict__ fc = fb + c * (H_ * W_);
        float acc = 0.0f;
        #pragma unroll
        for (int j = 0; j < 2; ++j) {
            #pragma unroll
            for (int i = 0; i < 2; ++i) {
                const int s = (oy * 2 + j) * GRID_S + (ox * 2 + i);
                acc += s_w[0][s] * fc[s_idx[0][s]];
                acc += s_w[1][s] * fc[s_idx[1][s]];
                acc += s_w[2][s] * fc[s_idx[2][s]];
                acc += s_w[3][s] * fc[s_idx[3][s]];
            }
        }
        ob[e] = acc;
    }
}

extern "C" void kernel_launch(void* const* d_in, const int* in_sizes, int n_in,
                              void* d_out, int out_size, void* d_ws, size_t ws_size,
                              hipStream_t stream) {
    const float* feat = (const float*)d_in[0];
    const float* rois = (const float*)d_in[1];
    float* out = (float*)d_out;
    const int N = in_sizes[1] / 6;  // 1000

    const size_t perm_bytes = (size_t)((N + 7) & ~7) * sizeof(int);
    const size_t need = FEATT_BYTES + perm_bytes;
    if (ws_size >= need && N >= 8) {
        __half* featT = (__half*)d_ws;
        int* perm = (int*)((char*)d_ws + FEATT_BYTES);
        dim3 tg(H_ * B_, C_ / 64, (W_ + 63) / 64);   // (400, 4, 4): iy fastest
        transpose_h_kernel<<<tg, 256, 0, stream>>>(feat, featT, rois, perm, N);
        const int nblk = 8 * ((N + 7) / 8);
        roi_main_nhwc_h<<<nblk, 256, 0, stream>>>(featT, rois, perm, N, out);
    } else {
        roi_main_nchw<<<N, 256, 0, stream>>>(feat, rois, out);
    }
}